// Round 1
// baseline (894.663 us; speedup 1.0000x reference)
//
#include <hip/hip_runtime.h>

// EM recurrent cross-attention, MI355X (gfx950).
// C=32 clusters, H=4 heads, F=64 features, N=200000 points, 2 EM steps.
// Strategy: one kernel per EM step (serial dependency through the centroid).
// Per step: HBM floor = K+V = 410MB. Per wave: 64 n's, one head.
//   Phase 1: lane=n, in-register scores s[32] + in-lane softmax (no reductions).
//   LDS transpose of w (per-wave private buffer).
//   Phase 2: lane=f, register accumulator acc[32], w via LDS broadcasts.
// Block reduce + global atomicAdd into zeroed output.

#define CC 32
#define HH 4
#define FF 64
#define NB 64
#define WAVES 4
#define BLOCK 256
#define GX 192   // grid.x -> 192*4 heads = 768 blocks = 3 blocks/CU

__global__ __launch_bounds__(BLOCK, 3) void em_step_kernel(
    const float* __restrict__ cent_in,   // (C,H,F)
    const float* __restrict__ Kp,        // (N,H,F)
    const float* __restrict__ Vp,        // (N,H,F)
    float* __restrict__ cent_out,        // (C,H,F), pre-zeroed; atomicAdd target
    int N)
{
    const int h    = blockIdx.y;
    const int tid  = threadIdx.x;
    const int wid  = tid >> 6;
    const int lane = tid & 63;

    __shared__ float cent[CC][FF];            // 8 KB, scaled by 1/sqrt(F)
    __shared__ float wlds[WAVES][NB][36];     // 36 KB; pad 36 floats = 144B (16B aligned)

    // stage centroid for this head, fold in the 1/sqrt(F)=0.125 score scale
    #pragma unroll
    for (int k = 0; k < (CC * FF) / BLOCK; ++k) {
        int i = k * BLOCK + tid;              // 0..2047
        int c = i >> 6, f = i & 63;
        cent[c][f] = cent_in[(c * HH + h) * FF + f] * 0.125f;
    }
    __syncthreads();

    float acc[CC];
    #pragma unroll
    for (int c = 0; c < CC; ++c) acc[c] = 0.f;

    const int ngroups = (N + NB - 1) / NB;    // 3125 for N=200000

    for (int g = blockIdx.x * WAVES + wid; g < ngroups; g += GX * WAVES) {
        const int n0 = g * NB;

        // ---------- phase 1: scores for n = n0 + lane ----------
        const int  n     = n0 + lane;
        const bool valid = (n < N);
        const int  ncl   = valid ? n : (N - 1);
        const float4* Kr = (const float4*)(Kp + ((size_t)ncl * HH + h) * FF);

        float s[CC];
        #pragma unroll
        for (int c = 0; c < CC; ++c) s[c] = 0.f;

        #pragma unroll 4
        for (int f4 = 0; f4 < FF / 4; ++f4) {
            float4 k4 = Kr[f4];
            #pragma unroll
            for (int c = 0; c < CC; ++c) {
                float4 ce = *(const float4*)&cent[c][f4 * 4];  // LDS broadcast
                s[c] = fmaf(k4.x, ce.x, s[c]);
                s[c] = fmaf(k4.y, ce.y, s[c]);
                s[c] = fmaf(k4.z, ce.z, s[c]);
                s[c] = fmaf(k4.w, ce.w, s[c]);
            }
        }

        // ---------- in-lane softmax over the 32 clusters ----------
        float m = s[0];
        #pragma unroll
        for (int c = 1; c < CC; ++c) m = fmaxf(m, s[c]);
        float sum = 0.f;
        #pragma unroll
        for (int c = 0; c < CC; ++c) { s[c] = __expf(s[c] - m); sum += s[c]; }
        float r = 1.0f / sum;
        if (!valid) r = 0.f;                 // OOB n contributes nothing

        float4* wr = (float4*)&wlds[wid][lane][0];
        #pragma unroll
        for (int c4 = 0; c4 < 8; ++c4) {
            float4 w4;
            w4.x = s[c4 * 4 + 0] * r;
            w4.y = s[c4 * 4 + 1] * r;
            w4.z = s[c4 * 4 + 2] * r;
            w4.w = s[c4 * 4 + 3] * r;
            wr[c4] = w4;                     // same-wave produce/consume: no barrier
        }

        // ---------- phase 2: acc[c][f=lane] += w[c][j] * V[j][f] ----------
        #pragma unroll 4
        for (int j = 0; j < NB; ++j) {
            int nj  = n0 + j;
            int njc = nj < N ? nj : (N - 1);
            float v = Vp[((size_t)njc * HH + h) * FF + lane];  // coalesced
            #pragma unroll
            for (int c4 = 0; c4 < 8; ++c4) {
                float4 w4 = *(const float4*)&wlds[wid][j][c4 * 4];  // broadcast
                acc[c4 * 4 + 0] = fmaf(w4.x, v, acc[c4 * 4 + 0]);
                acc[c4 * 4 + 1] = fmaf(w4.y, v, acc[c4 * 4 + 1]);
                acc[c4 * 4 + 2] = fmaf(w4.z, v, acc[c4 * 4 + 2]);
                acc[c4 * 4 + 3] = fmaf(w4.w, v, acc[c4 * 4 + 3]);
            }
        }
    }

    // ---------- block reduce (overlay scratch on wlds) + global atomics ----------
    __syncthreads();
    float* red = &wlds[0][0][0];             // need 4*32*64 floats = 32KB <= 36KB
    #pragma unroll
    for (int c = 0; c < CC; ++c) red[(wid * CC + c) * FF + lane] = acc[c];
    __syncthreads();
    #pragma unroll
    for (int k = 0; k < (CC * FF) / BLOCK; ++k) {
        int o = k * BLOCK + tid;             // 0..2047
        int c = o >> 6, f = o & 63;
        float val = red[(0 * CC + c) * FF + f]
                  + red[(1 * CC + c) * FF + f]
                  + red[(2 * CC + c) * FF + f]
                  + red[(3 * CC + c) * FF + f];
        atomicAdd(&cent_out[(c * HH + h) * FF + f], val);
    }
}

extern "C" void kernel_launch(void* const* d_in, const int* in_sizes, int n_in,
                              void* d_out, int out_size, void* d_ws, size_t ws_size,
                              hipStream_t stream)
{
    const float* Q = (const float*)d_in[0];   // (C,H,F)
    const float* K = (const float*)d_in[1];   // (N,H,F)
    const float* V = (const float*)d_in[2];   // (N,H,F)
    float*       out   = (float*)d_out;       // (C,H,F)
    float*       cent1 = (float*)d_ws;        // step-1 centroid accumulator

    const int N = in_sizes[1] / (HH * FF);

    hipMemsetAsync(cent1, 0, CC * HH * FF * sizeof(float), stream);
    hipMemsetAsync(out,   0, CC * HH * FF * sizeof(float), stream);

    dim3 grid(GX, HH), block(BLOCK);
    em_step_kernel<<<grid, block, 0, stream>>>(Q,     K, V, cent1, N);  // EM step 1
    em_step_kernel<<<grid, block, 0, stream>>>(cent1, K, V, out,   N);  // EM step 2
}

// Round 2
// 727.747 us; speedup vs baseline: 1.2294x; 1.2294x over previous
//
#include <hip/hip_runtime.h>

// EM recurrent cross-attention, MI355X (gfx950). Round 2.
// C=32, H=4, F=64, N=200000, 2 EM steps (one kernel launch each).
// R1 was latency-bound (VALUBusy 26%, occ 28%, HBM 8%). Fixes:
//  - 512-thread blocks, 80KB LDS -> 2 blocks/CU -> 16 waves/CU (was ~9)
//  - v_pk_fma_f32 (packed fp32) halves FMA issue in both phases
//  - explicit double-buffered V prefetch in phase 2
// Per wave: 64 n's. Phase1 lane=n (in-lane softmax), LDS transpose of w,
// phase2 lane=f with register acc. Block reduce + atomicAdd epilogue.

#define CC 32
#define HH 4
#define FF 64
#define NB 64
#define WAVES 8
#define BLOCK 512
#define GX 128   // 128*4 heads = 512 blocks = 2/CU exactly

typedef float f32x2 __attribute__((ext_vector_type(2)));

__device__ __forceinline__ void pkfma(f32x2& d, f32x2 a, f32x2 b) {
    // D.lo = fma(a.lo,b.lo,D.lo); D.hi = fma(a.hi,b.hi,D.hi)
    asm("v_pk_fma_f32 %0, %1, %2, %0" : "+v"(d) : "v"(a), "v"(b));
}

__global__ __launch_bounds__(BLOCK, 4) void em_step_kernel(
    const float* __restrict__ cent_in,   // (C,H,F)
    const float* __restrict__ Kp,        // (N,H,F)
    const float* __restrict__ Vp,        // (N,H,F)
    float* __restrict__ cent_out,        // (C,H,F), pre-zeroed atomicAdd target
    int N)
{
    const int h    = blockIdx.y;
    const int tid  = threadIdx.x;
    const int wid  = tid >> 6;
    const int lane = tid & 63;

    __shared__ float centT[FF][CC];            // 8 KB, transposed [f][c], ×0.125
    __shared__ float wlds[WAVES][NB][36];      // 72 KB (pad 36 -> 16B-aligned rows)

    // stage centroid transposed; fold in 1/sqrt(F)=0.125
    for (int i = tid; i < CC * FF; i += BLOCK) {
        int c = i & (CC - 1), f = i >> 5;
        centT[f][c] = cent_in[(c * HH + h) * FF + f] * 0.125f;
    }
    __syncthreads();

    f32x2 acc2[16];                            // acc2[p] = {acc[2p], acc[2p+1]}, lane=f
    #pragma unroll
    for (int p = 0; p < 16; ++p) acc2[p] = f32x2{0.f, 0.f};

    const int ngroups = (N + NB - 1) / NB;     // 3125

    for (int g = blockIdx.x * WAVES + wid; g < ngroups; g += GX * WAVES) {
        const int n0 = g * NB;

        // ---------- phase 1: scores for n = n0 + lane ----------
        const int  n     = n0 + lane;
        const bool valid = (n < N);
        const int  ncl   = valid ? n : (N - 1);
        const float4* Kr = (const float4*)(Kp + ((size_t)ncl * HH + h) * FF);

        f32x2 s2[16];                          // s2[p] = {s[2p], s[2p+1]}
        #pragma unroll
        for (int p = 0; p < 16; ++p) s2[p] = f32x2{0.f, 0.f};

        #pragma unroll 4
        for (int f4 = 0; f4 < FF / 4; ++f4) {
            float4 k4 = Kr[f4];
            float kv[4] = {k4.x, k4.y, k4.z, k4.w};
            #pragma unroll
            for (int ff = 0; ff < 4; ++ff) {
                f32x2 kk = {kv[ff], kv[ff]};
                const float4* crow = (const float4*)&centT[f4 * 4 + ff][0];
                #pragma unroll
                for (int c8 = 0; c8 < 8; ++c8) {
                    float4 ce = crow[c8];      // uniform addr -> LDS broadcast
                    pkfma(s2[c8 * 2 + 0], kk, f32x2{ce.x, ce.y});
                    pkfma(s2[c8 * 2 + 1], kk, f32x2{ce.z, ce.w});
                }
            }
        }

        // ---------- in-lane softmax over 32 clusters ----------
        float m = -3.0e38f;
        #pragma unroll
        for (int p = 0; p < 16; ++p) m = fmaxf(m, fmaxf(s2[p].x, s2[p].y));
        float sum = 0.f;
        #pragma unroll
        for (int p = 0; p < 16; ++p) {
            s2[p].x = __expf(s2[p].x - m); sum += s2[p].x;
            s2[p].y = __expf(s2[p].y - m); sum += s2[p].y;
        }
        float r = 1.0f / sum;
        if (!valid) r = 0.f;

        float4* wr = (float4*)&wlds[wid][lane][0];
        #pragma unroll
        for (int c4 = 0; c4 < 8; ++c4) {
            float4 w4;
            w4.x = s2[2 * c4].x     * r;
            w4.y = s2[2 * c4].y     * r;
            w4.z = s2[2 * c4 + 1].x * r;
            w4.w = s2[2 * c4 + 1].y * r;
            wr[c4] = w4;                       // same-wave produce/consume
        }

        // ---------- phase 2: acc[c][f=lane] += w[j][c] * V[j][f] ----------
        const float* Vb = Vp + (size_t)h * FF + lane;

        auto loadv = [&](float (&buf)[16], int jbase) {
            #pragma unroll
            for (int jj = 0; jj < 16; ++jj) {
                int nj  = n0 + jbase + jj;
                int njc = nj < N ? nj : (N - 1);
                buf[jj] = Vb[(size_t)njc * (HH * FF)];   // coalesced
            }
        };
        auto pv = [&](const float (&buf)[16], int jbase) {
            #pragma unroll
            for (int jj = 0; jj < 16; ++jj) {
                int j = jbase + jj;
                f32x2 vv = {buf[jj], buf[jj]};
                const float4* wrow = (const float4*)&wlds[wid][j][0];
                #pragma unroll
                for (int c4 = 0; c4 < 8; ++c4) {
                    float4 w4 = wrow[c4];      // uniform addr -> LDS broadcast
                    pkfma(acc2[2 * c4 + 0], vv, f32x2{w4.x, w4.y});
                    pkfma(acc2[2 * c4 + 1], vv, f32x2{w4.z, w4.w});
                }
            }
        };

        float va[16], vb[16];
        loadv(va, 0);                          // software pipeline: load ahead,
        loadv(vb, 16);                         // compute behind
        pv(va, 0);
        loadv(va, 32);
        pv(vb, 16);
        loadv(vb, 48);
        pv(va, 32);
        pv(vb, 48);
    }

    // ---------- block reduce (overlay on wlds) + global atomics ----------
    __syncthreads();
    float* red = &wlds[0][0][0];               // need 8*32*64 floats = 64KB <= 72KB
    #pragma unroll
    for (int p = 0; p < 16; ++p) {
        red[(wid * CC + 2 * p + 0) * FF + lane] = acc2[p].x;
        red[(wid * CC + 2 * p + 1) * FF + lane] = acc2[p].y;
    }
    __syncthreads();
    #pragma unroll
    for (int k = 0; k < (CC * FF) / BLOCK; ++k) {   // 4 iters
        int o = k * BLOCK + tid;
        int c = o >> 6, f = o & 63;
        float val = 0.f;
        #pragma unroll
        for (int w = 0; w < WAVES; ++w) val += red[(w * CC + c) * FF + f];
        atomicAdd(&cent_out[(c * HH + h) * FF + f], val);
    }
}

extern "C" void kernel_launch(void* const* d_in, const int* in_sizes, int n_in,
                              void* d_out, int out_size, void* d_ws, size_t ws_size,
                              hipStream_t stream)
{
    const float* Q = (const float*)d_in[0];   // (C,H,F)
    const float* K = (const float*)d_in[1];   // (N,H,F)
    const float* V = (const float*)d_in[2];   // (N,H,F)
    float*       out   = (float*)d_out;       // (C,H,F)
    float*       cent1 = (float*)d_ws;        // step-1 centroid accumulator

    const int N = in_sizes[1] / (HH * FF);

    hipMemsetAsync(cent1, 0, CC * HH * FF * sizeof(float), stream);
    hipMemsetAsync(out,   0, CC * HH * FF * sizeof(float), stream);

    dim3 grid(GX, HH), block(BLOCK);
    em_step_kernel<<<grid, block, 0, stream>>>(Q,     K, V, cent1, N);  // EM step 1
    em_step_kernel<<<grid, block, 0, stream>>>(cent1, K, V, out,   N);  // EM step 2
}